// Round 1
// baseline (223.715 us; speedup 1.0000x reference)
//
#include <hip/hip_runtime.h>

// RelativeMultiHeadAttention on MI355X (gfx950)
// Pipeline: cast_x, cast_w -> proj_gemm<0> (QKV, bf16 MFMA) -> rel_attn (flash, LDS bias table)
//           -> proj_gemm<1> (out proj, fp32 out + bias)
// ws layout (bytes):
//   [0,          8388608)  x_bf16   [16384][256] bf16   (reused as attn_out after attention)
//   [8388608,    8912896)  Wcat     [1024][256]  bf16   rows: Wq|Wk|Wv|Wo
//   [8912896,   17301504)  q_buf    [128][1024][32] bf16 (scale folded in)
//   [17301504,  25690112)  k_buf    [128][1024][32] bf16
//   [25690112,  34078720)  v_t      [128][32][1024] bf16 (transposed for PV B-frags)

typedef unsigned short u16;
typedef short short8 __attribute__((ext_vector_type(8)));
typedef u16 u16x8 __attribute__((ext_vector_type(8)));
typedef u16 u16x4 __attribute__((ext_vector_type(4)));
typedef float f32x4 __attribute__((ext_vector_type(4)));

#define QSCALE 0.17677669529663687f
#define NREL 3969

__device__ __forceinline__ u16 f2bf(float f) {
  union { float f; unsigned u; } x; x.f = f;
  unsigned r = x.u + 0x7fffu + ((x.u >> 16) & 1u);
  return (u16)(r >> 16);
}

__global__ __launch_bounds__(256) void cast_x_k(const float4* __restrict__ in,
                                                u16x4* __restrict__ out, int n4) {
  int i = blockIdx.x * 256 + threadIdx.x;
  if (i < n4) {
    float4 v = in[i];
    u16x4 o;
    o[0] = f2bf(v.x); o[1] = f2bf(v.y); o[2] = f2bf(v.z); o[3] = f2bf(v.w);
    out[i] = o;
  }
}

__global__ __launch_bounds__(256) void cast_w_k(const float* __restrict__ wq,
                                                const float* __restrict__ wk,
                                                const float* __restrict__ wv,
                                                const float* __restrict__ wo,
                                                u16x4* __restrict__ out) {
  int i = blockIdx.x * 256 + threadIdx.x;  // 0..65535 float4 units (4 x 16384)
  int wi = i >> 14, off = i & 16383;
  const float* src = (wi == 0) ? wq : (wi == 1) ? wk : (wi == 2) ? wv : wo;
  float4 v = ((const float4*)src)[off];
  u16x4 o;
  o[0] = f2bf(v.x); o[1] = f2bf(v.y); o[2] = f2bf(v.z); o[3] = f2bf(v.w);
  out[i] = o;
}

// MODE 0: A=x_bf16, cols 0..767 of Wcat (Wq|Wk|Wv) -> q_buf / k_buf / v_t (bf16)
// MODE 1: A=attn_out, cols 768..1023 (Wo) -> fp32 out + bo
template <int MODE>
__global__ __launch_bounds__(256) void proj_gemm_k(
    const u16* __restrict__ A, const u16* __restrict__ Wc,
    const float* __restrict__ b0, const float* __restrict__ b1,
    const float* __restrict__ b2,
    u16* __restrict__ qb, u16* __restrict__ kb, u16* __restrict__ vtb,
    float* __restrict__ outp) {
  const int NT = (MODE == 0) ? 12 : 4;
  const int m0 = (blockIdx.x / NT) * 64;
  const int n0 = (blockIdx.x % NT) * 64;
  const int wrow0 = (MODE == 0) ? n0 : (768 + n0);
  __shared__ u16 Al[64 * 32];
  __shared__ u16 Bl[64 * 32];
  const int tid = threadIdx.x;
  const int wave = tid >> 6, lane = tid & 63;
  const int fr = lane & 15, kg = lane >> 4;
  const int srow = tid >> 2, sseg = tid & 3;
  const int sw_w = (sseg * 16) ^ ((srow & 3) << 4);  // 64B rows -> 2-bit swizzle
  const int sw_r = (kg * 16) ^ ((fr & 3) << 4);
  f32x4 acc[4];
#pragma unroll
  for (int g = 0; g < 4; ++g) acc[g] = (f32x4){0.f, 0.f, 0.f, 0.f};

  for (int k0 = 0; k0 < 256; k0 += 32) {
    u16x8 av = *(const u16x8*)(A + (m0 + srow) * 256 + k0 + sseg * 8);
    u16x8 wv = *(const u16x8*)(Wc + (wrow0 + srow) * 256 + k0 + sseg * 8);
    *(u16x8*)((char*)Al + srow * 64 + sw_w) = av;
    *(u16x8*)((char*)Bl + srow * 64 + sw_w) = wv;
    __syncthreads();
    short8 af = *(const short8*)((char*)Al + (wave * 16 + fr) * 64 + sw_r);
#pragma unroll
    for (int g = 0; g < 4; ++g) {
      short8 bf = *(const short8*)((char*)Bl + (g * 16 + fr) * 64 + sw_r);
      acc[g] = __builtin_amdgcn_mfma_f32_16x16x32_bf16(af, bf, acc[g], 0, 0, 0);
    }
    __syncthreads();
  }

  if (MODE == 0) {
    const int ws = n0 >> 8;   // 0=q 1=k 2=v, uniform per block
    const int nb = n0 & 255;
#pragma unroll
    for (int g = 0; g < 4; ++g) {
      const int n = nb + g * 16 + fr;
      const int h = n >> 5, d = n & 31;
      const float bias = (ws == 0) ? b0[n] : (ws == 1) ? b1[n] : b2[n];
      if (ws == 2) {
        const int m = m0 + wave * 16 + kg * 4;
        const int b = m >> 10, s = m & 1023;
        u16x4 pk;
#pragma unroll
        for (int r = 0; r < 4; ++r) pk[r] = f2bf(acc[g][r] + bias);
        *(u16x4*)(vtb + ((b * 8 + h) * 32 + d) * 1024 + s) = pk;  // 4 consecutive s
      } else {
        u16* dst = (ws == 0) ? qb : kb;
        const float sc = (ws == 0) ? QSCALE : 1.0f;
#pragma unroll
        for (int r = 0; r < 4; ++r) {
          const int m = m0 + wave * 16 + kg * 4 + r;
          const int b = m >> 10, s = m & 1023;
          dst[((b * 8 + h) * 1024 + s) * 32 + d] = f2bf((acc[g][r] + bias) * sc);
        }
      }
    }
  } else {
#pragma unroll
    for (int g = 0; g < 4; ++g) {
      const int n = n0 + g * 16 + fr;
      const float bias = b0[n];
#pragma unroll
      for (int r = 0; r < 4; ++r) {
        const int m = m0 + wave * 16 + kg * 4 + r;
        outp[m * 256 + n] = acc[g][r] + bias;
      }
    }
  }
}

// grid: (B*H)*16 blocks; block = 4 waves; wave w owns 16 q-rows of a 64-query tile.
__global__ __launch_bounds__(256) void rel_attn_k(
    const u16* __restrict__ qb, const u16* __restrict__ kb,
    const u16* __restrict__ vtb, const float* __restrict__ btab,
    u16* __restrict__ ao) {
  const int bh = blockIdx.x >> 4;
  const int qt = blockIdx.x & 15;
  const int h = bh & 7;
  const int b = bh >> 3;
  const int q0 = qt * 64;
  __shared__ float bias_l[NREL + 3];
  __shared__ u16 Kl[64 * 32];        // [key][d], 64B rows, 2-bit swizzle
  __shared__ u16 Vl[32 * 64];        // [d][key], 128B rows, 3-bit swizzle
  __shared__ u16 Pl[4][16 * 64];     // per-wave P tile [qrow][key], 128B rows
  const int tid = threadIdx.x;
  const int wave = tid >> 6, lane = tid & 63;
  const int fr = lane & 15, kg = lane >> 4;

  for (int i = tid; i < NREL; i += 256) bias_l[i] = btab[h * NREL + i];

  const short8 qf = *(const short8*)(qb + (bh * 1024 + q0 + wave * 16 + fr) * 32 + kg * 8);
  const int qrb = q0 + wave * 16 + kg * 4;  // D-layout row base for this lane

  float m_r[4], l_r[4];
  f32x4 oacc[2];
#pragma unroll
  for (int r = 0; r < 4; ++r) { m_r[r] = -1e30f; l_r[r] = 0.f; }
  oacc[0] = (f32x4){0.f, 0.f, 0.f, 0.f};
  oacc[1] = (f32x4){0.f, 0.f, 0.f, 0.f};

  const int stg_key = tid >> 2, stg_seg = tid & 3;
  const int stg_d = tid >> 3, stg_s2 = tid & 7;
  __syncthreads();  // bias_l ready

  for (int kt = 0; kt < 16; ++kt) {
    const int k0 = kt * 64;
    u16x8 kv = *(const u16x8*)(kb + (bh * 1024 + k0 + stg_key) * 32 + stg_seg * 8);
    *(u16x8*)((char*)Kl + stg_key * 64 + ((stg_seg * 16) ^ ((stg_key & 3) << 4))) = kv;
    u16x8 vv = *(const u16x8*)(vtb + (bh * 32 + stg_d) * 1024 + k0 + stg_s2 * 8);
    *(u16x8*)((char*)Vl + stg_d * 128 + ((stg_s2 * 16) ^ ((stg_d & 7) << 4))) = vv;
    __syncthreads();

    // S = q . k  (scale already folded into q)
    f32x4 sacc[4];
#pragma unroll
    for (int g = 0; g < 4; ++g) {
      short8 kf = *(const short8*)((char*)Kl + (g * 16 + fr) * 64 + ((kg * 16) ^ ((fr & 3) << 4)));
      sacc[g] = __builtin_amdgcn_mfma_f32_16x16x32_bf16(qf, kf, (f32x4){0.f, 0.f, 0.f, 0.f}, 0, 0, 0);
    }

    // + relative position bias (analytic index into LDS table), track row max
    float pmax[4] = {-1e30f, -1e30f, -1e30f, -1e30f};
#pragma unroll
    for (int g = 0; g < 4; ++g) {
      const int kc = k0 + g * 16 + fr;
      const int ki = kc >> 5, kj = kc & 31;
#pragma unroll
      for (int r = 0; r < 4; ++r) {
        const int qq = qrb + r;
        const float v = sacc[g][r] + bias_l[((qq >> 5) - ki + 31) * 63 + ((qq & 31) - kj + 31)];
        sacc[g][r] = v;
        pmax[r] = fmaxf(pmax[r], v);
      }
    }
#pragma unroll
    for (int off = 8; off; off >>= 1)
#pragma unroll
      for (int r = 0; r < 4; ++r) pmax[r] = fmaxf(pmax[r], __shfl_xor(pmax[r], off));

    float fac[4], psum[4];
#pragma unroll
    for (int r = 0; r < 4; ++r) {
      const float mn = fmaxf(m_r[r], pmax[r]);
      fac[r] = __expf(m_r[r] - mn);
      m_r[r] = mn;
      psum[r] = 0.f;
    }
    // P = exp(S - m), stage to LDS (bf16) for the PV A-fragment
#pragma unroll
    for (int g = 0; g < 4; ++g) {
#pragma unroll
      for (int r = 0; r < 4; ++r) {
        const float p = __expf(sacc[g][r] - m_r[r]);
        psum[r] += p;
        const int row = kg * 4 + r;
        *(u16*)((char*)Pl[wave] + row * 128 + ((g * 32 + fr * 2) ^ ((row & 7) << 4))) = f2bf(p);
      }
    }
#pragma unroll
    for (int off = 8; off; off >>= 1)
#pragma unroll
      for (int r = 0; r < 4; ++r) psum[r] += __shfl_xor(psum[r], off);
#pragma unroll
    for (int r = 0; r < 4; ++r) l_r[r] = l_r[r] * fac[r] + psum[r];
#pragma unroll
    for (int g2 = 0; g2 < 2; ++g2)
#pragma unroll
      for (int r = 0; r < 4; ++r) oacc[g2][r] *= fac[r];
    __syncthreads();  // P visible; all waves past Kl reads

    // O += P . V
#pragma unroll
    for (int ks = 0; ks < 2; ++ks) {
      const short8 pf = *(const short8*)((char*)Pl[wave] + fr * 128 + ((ks * 64 + kg * 16) ^ ((fr & 7) << 4)));
#pragma unroll
      for (int g2 = 0; g2 < 2; ++g2) {
        const short8 vf = *(const short8*)((char*)Vl + (g2 * 16 + fr) * 128 + ((ks * 64 + kg * 16) ^ ((fr & 7) << 4)));
        oacc[g2] = __builtin_amdgcn_mfma_f32_16x16x32_bf16(pf, vf, oacc[g2], 0, 0, 0);
      }
    }
    __syncthreads();  // PV done reading Vl before next stage
  }

#pragma unroll
  for (int g2 = 0; g2 < 2; ++g2) {
#pragma unroll
    for (int r = 0; r < 4; ++r) {
      const float val = oacc[g2][r] / l_r[r];
      ao[(b * 1024 + qrb + r) * 256 + h * 32 + g2 * 16 + fr] = f2bf(val);
    }
  }
}

extern "C" void kernel_launch(void* const* d_in, const int* in_sizes, int n_in,
                              void* d_out, int out_size, void* d_ws, size_t ws_size,
                              hipStream_t stream) {
  (void)in_sizes; (void)n_in; (void)out_size; (void)ws_size;
  const float* x    = (const float*)d_in[0];
  const float* Wq   = (const float*)d_in[1];
  const float* bq   = (const float*)d_in[2];
  const float* Wk   = (const float*)d_in[3];
  const float* bk   = (const float*)d_in[4];
  const float* Wv   = (const float*)d_in[5];
  const float* bv   = (const float*)d_in[6];
  const float* Wo   = (const float*)d_in[7];
  const float* bo   = (const float*)d_in[8];
  const float* btab = (const float*)d_in[9];
  // d_in[10] (rel_index) intentionally unused: recomputed analytically in-kernel.
  float* out = (float*)d_out;
  char* ws = (char*)d_ws;

  u16* xbf  = (u16*)(ws + 0);          // also attn_out after rel_attn_k
  u16* Wcat = (u16*)(ws + 8388608);
  u16* qbuf = (u16*)(ws + 8912896);
  u16* kbuf = (u16*)(ws + 17301504);
  u16* vtb  = (u16*)(ws + 25690112);

  cast_x_k<<<4096, 256, 0, stream>>>((const float4*)x, (u16x4*)xbf, 1048576);
  cast_w_k<<<256, 256, 0, stream>>>(Wq, Wk, Wv, Wo, (u16x4*)Wcat);
  proj_gemm_k<0><<<3072, 256, 0, stream>>>(xbf, Wcat, bq, bk, bv, qbuf, kbuf, vtb, nullptr);
  rel_attn_k<<<2048, 256, 0, stream>>>(qbuf, kbuf, vtb, btab, xbf);
  proj_gemm_k<1><<<1024, 256, 0, stream>>>(xbf, Wcat, bo, nullptr, nullptr,
                                           nullptr, nullptr, nullptr, out);
}

// Round 2
// 219.589 us; speedup vs baseline: 1.0188x; 1.0188x over previous
//
#include <hip/hip_runtime.h>

// RelativeMultiHeadAttention on MI355X (gfx950)
// cast_x, cast_w -> proj_gemm<0> (QKV, 128x128 MFMA, global_load_lds) ->
// rel_attn (flash, swapped-QK, barrier-free k-loop) -> proj_gemm<1> (out+bias)
// ws layout (bytes):
//   [0,          8388608)  x_bf16   [16384][256] bf16   (reused as attn_out)
//   [8388608,    8912896)  Wcat     [1024][256]  bf16   rows: Wq|Wk|Wv|Wo
//   [8912896,   17301504)  q_buf    [128][1024][32] bf16 (scale*log2e folded)
//   [17301504,  25690112)  k_buf    [128][1024][32] bf16
//   [25690112,  34078720)  v_t      [128][32][1024] bf16

typedef unsigned short u16;
typedef unsigned int u32;
typedef short short8 __attribute__((ext_vector_type(8)));
typedef u16 u16x4 __attribute__((ext_vector_type(4)));
typedef u32 u32x2 __attribute__((ext_vector_type(2)));
typedef float f32x4 __attribute__((ext_vector_type(4)));

#define NREL 3969
#define LOG2E 1.4426950408889634f
#define QS2 (0.17677669529663687f * 1.4426950408889634f)

__device__ __forceinline__ u16 f2bf(float f) {
  union { float f; unsigned u; } x; x.f = f;
  unsigned r = x.u + 0x7fffu + ((x.u >> 16) & 1u);
  return (u16)(r >> 16);
}

__device__ __forceinline__ u32 cvt_pk_bf16(float lo, float hi) {
  u32 r;
  asm("v_cvt_pk_bf16_f32 %0, %1, %2" : "=v"(r) : "v"(lo), "v"(hi));
  return r;
}

__device__ __forceinline__ float fast_exp2(float x) {
  float r;
  asm("v_exp_f32 %0, %1" : "=v"(r) : "v"(x));
  return r;
}

__device__ __forceinline__ void glds16(const u16* g, u16* l) {
  __builtin_amdgcn_global_load_lds((const __attribute__((address_space(1))) u32*)g,
                                   (__attribute__((address_space(3))) u32*)l, 16, 0, 0);
}

__global__ __launch_bounds__(256) void cast_x_k(const float4* __restrict__ in,
                                                u16x4* __restrict__ out, int n4) {
  int i = blockIdx.x * 256 + threadIdx.x;
  if (i < n4) {
    float4 v = in[i];
    u16x4 o;
    o[0] = f2bf(v.x); o[1] = f2bf(v.y); o[2] = f2bf(v.z); o[3] = f2bf(v.w);
    out[i] = o;
  }
}

__global__ __launch_bounds__(256) void cast_w_k(const float* __restrict__ wq,
                                                const float* __restrict__ wk,
                                                const float* __restrict__ wv,
                                                const float* __restrict__ wo,
                                                u16x4* __restrict__ out) {
  int i = blockIdx.x * 256 + threadIdx.x;
  int wi = i >> 14, off = i & 16383;
  const float* src = (wi == 0) ? wq : (wi == 1) ? wk : (wi == 2) ? wv : wo;
  float4 v = ((const float4*)src)[off];
  u16x4 o;
  o[0] = f2bf(v.x); o[1] = f2bf(v.y); o[2] = f2bf(v.z); o[3] = f2bf(v.w);
  out[i] = o;
}

// 128x128 tile, 4 waves (2x2 of 64x64), BK=32, global_load_lds w/ pre-swizzled src.
// MODE 0: A=x_bf16, Wcat rows 0..767 -> q(scaled)/k/v_t.  MODE 1: rows 768..1023 -> f32 out.
template <int MODE>
__global__ __launch_bounds__(256, 4) void proj_gemm_k(
    const u16* __restrict__ A, const u16* __restrict__ Wc,
    const float* __restrict__ b0, const float* __restrict__ b1,
    const float* __restrict__ b2,
    u16* __restrict__ qb, u16* __restrict__ kb, u16* __restrict__ vtb,
    float* __restrict__ outp) {
  const int NT = (MODE == 0) ? 6 : 2;
  const int m0 = (blockIdx.x / NT) * 128;
  const int n0 = (blockIdx.x % NT) * 128;
  const int wrow0 = (MODE == 0) ? n0 : (768 + n0);
  __shared__ u16 Al[128 * 32];
  __shared__ u16 Bl[128 * 32];
  const int tid = threadIdx.x;
  const int wave = tid >> 6, lane = tid & 63;
  const int fr = lane & 15, kg = lane >> 4;
  const int wm = wave >> 1, wn = wave & 1;
  const int srow = lane >> 2;                       // row within 16-row segment
  const int scol = ((lane & 3) ^ (srow & 3)) * 8;   // pre-swizzled source col (u16)
  const u16* gA0 = A + (m0 + wave * 16 + srow) * 256 + scol;
  const u16* gA1 = A + (m0 + (wave + 4) * 16 + srow) * 256 + scol;
  const u16* gB0 = Wc + (wrow0 + wave * 16 + srow) * 256 + scol;
  const u16* gB1 = Wc + (wrow0 + (wave + 4) * 16 + srow) * 256 + scol;
  u16* lA0 = &Al[wave * 512];
  u16* lA1 = &Al[(wave + 4) * 512];
  u16* lB0 = &Bl[wave * 512];
  u16* lB1 = &Bl[(wave + 4) * 512];
  const int rsw = (kg * 16) ^ ((fr & 3) << 4);      // swizzled read byte-in-row

  f32x4 acc[4][4];
#pragma unroll
  for (int i = 0; i < 4; ++i)
#pragma unroll
    for (int j = 0; j < 4; ++j) acc[i][j] = (f32x4){0.f, 0.f, 0.f, 0.f};

  for (int k0 = 0; k0 < 256; k0 += 32) {
    glds16(gA0 + k0, lA0);
    glds16(gA1 + k0, lA1);
    glds16(gB0 + k0, lB0);
    glds16(gB1 + k0, lB1);
    __syncthreads();
    short8 af[4], bf[4];
#pragma unroll
    for (int i = 0; i < 4; ++i) {
      af[i] = *(const short8*)((const char*)Al + (wm * 64 + i * 16 + fr) * 64 + rsw);
      bf[i] = *(const short8*)((const char*)Bl + (wn * 64 + i * 16 + fr) * 64 + rsw);
    }
#pragma unroll
    for (int mi = 0; mi < 4; ++mi)
#pragma unroll
      for (int ni = 0; ni < 4; ++ni)
        acc[mi][ni] = __builtin_amdgcn_mfma_f32_16x16x32_bf16(af[mi], bf[ni], acc[mi][ni], 0, 0, 0);
    __syncthreads();
  }

  if (MODE == 0) {
    const int ws = (n0 + wn * 64) >> 8;   // 0=q 1=k 2=v, uniform per wave
    const int nbb = (n0 + wn * 64) & 255;
#pragma unroll
    for (int ni = 0; ni < 4; ++ni) {
      const int nb = nbb + ni * 16 + fr;
      const int h = nb >> 5, d = nb & 31;
      const float bias = (ws == 0) ? b0[nb] : (ws == 1) ? b1[nb] : b2[nb];
#pragma unroll
      for (int mi = 0; mi < 4; ++mi) {
        const int m = m0 + wm * 64 + mi * 16 + kg * 4;
        const int b = m >> 10, s = m & 1023;
        if (ws == 2) {
          u16x4 pk;
#pragma unroll
          for (int r = 0; r < 4; ++r) pk[r] = f2bf(acc[mi][ni][r] + bias);
          *(u16x4*)(vtb + ((b * 8 + h) * 32 + d) * 1024 + s) = pk;
        } else if (ws == 0) {
#pragma unroll
          for (int r = 0; r < 4; ++r)
            qb[((b * 8 + h) * 1024 + s + r) * 32 + d] = f2bf((acc[mi][ni][r] + bias) * QS2);
        } else {
#pragma unroll
          for (int r = 0; r < 4; ++r)
            kb[((b * 8 + h) * 1024 + s + r) * 32 + d] = f2bf(acc[mi][ni][r] + bias);
        }
      }
    }
  } else {
#pragma unroll
    for (int ni = 0; ni < 4; ++ni) {
      const int n = n0 + wn * 64 + ni * 16 + fr;
      const float bias = b0[n];
#pragma unroll
      for (int mi = 0; mi < 4; ++mi) {
#pragma unroll
        for (int r = 0; r < 4; ++r) {
          const int m = m0 + wm * 64 + mi * 16 + kg * 4 + r;
          outp[m * 256 + n] = acc[mi][ni][r] + bias;
        }
      }
    }
  }
}

// Flash attention, swapped QK^T (lane owns one q-row), barrier-free k-loop.
// grid: 2048 blocks (XCD-chunk-swizzled), 4 waves, wave owns 16 q-rows.
__global__ __launch_bounds__(256, 4) void rel_attn_k(
    const u16* __restrict__ qb, const u16* __restrict__ kb,
    const u16* __restrict__ vtb, const float* __restrict__ btab,
    u16* __restrict__ ao) {
  const int bid0 = blockIdx.x;
  const int lid = (bid0 & 7) * 256 + (bid0 >> 3);  // XCD chunking: same bh -> same XCD
  const int bh = lid >> 4, qt = lid & 15;
  const int h = bh & 7, b = bh >> 3;
  const int q0 = qt * 64;
  __shared__ float bias_l[NREL];
  __shared__ u16 Pl[4][16 * 64];
  const int tid = threadIdx.x;
  const int wave = tid >> 6, lane = tid & 63;
  const int fr = lane & 15, kg = lane >> 4;

  for (int i = tid; i < NREL; i += 256) bias_l[i] = btab[h * NREL + i] * LOG2E;

  const int q = q0 + wave * 16 + fr;               // this lane's q-row
  const short8 qf = *(const short8*)(qb + (bh * 1024 + q) * 32 + kg * 8);
  const int qbase = (q >> 5) * 63 + (q & 31) + 1984;
  const u16* kp = kb + (bh * 1024 + fr) * 32 + kg * 8;
  const u16* vp = vtb + (bh * 32 + fr) * 1024 + kg * 8;
  char* pw = (char*)Pl[wave] + fr * 128;
  const int swz = (fr & 7) << 4;

  float m_r = -1e30f, l_r = 0.f;
  f32x4 oacc[2];
  oacc[0] = (f32x4){0.f, 0.f, 0.f, 0.f};
  oacc[1] = (f32x4){0.f, 0.f, 0.f, 0.f};
  __syncthreads();  // bias_l ready; only barrier in the kernel

  for (int kt = 0; kt < 16; ++kt) {
    short8 kf[4];
#pragma unroll
    for (int g = 0; g < 4; ++g)
      kf[g] = *(const short8*)(kp + kt * 2048 + g * 512);
    short8 vf[2][2];
#pragma unroll
    for (int ks = 0; ks < 2; ++ks)
#pragma unroll
      for (int g2 = 0; g2 < 2; ++g2)
        vf[ks][g2] = *(const short8*)(vp + g2 * 16384 + kt * 64 + ks * 32);

    // S^T = K.Q (row=key=g*16+kg*4+r, col=q=fr); scale*log2e folded into q
    f32x4 sacc[4];
#pragma unroll
    for (int g = 0; g < 4; ++g)
      sacc[g] = __builtin_amdgcn_mfma_f32_16x16x32_bf16(kf[g], qf, (f32x4){0.f, 0.f, 0.f, 0.f}, 0, 0, 0);

    // + bias (analytic): idx = qbase - key - 31*ki, ki = 2*kt + (g>>1)
    const int t0 = qbase - kt * 126 - kg * 4;
    float mloc = -1e30f;
#pragma unroll
    for (int g = 0; g < 4; ++g) {
      const int ag = t0 - g * 16 - 31 * (g >> 1);
#pragma unroll
      for (int r = 0; r < 4; ++r) {
        const float v = sacc[g][r] + bias_l[ag - r];
        sacc[g][r] = v;
        mloc = fmaxf(mloc, v);
      }
    }
    mloc = fmaxf(mloc, __shfl_xor(mloc, 16));
    mloc = fmaxf(mloc, __shfl_xor(mloc, 32));
    const float mn = fmaxf(m_r, mloc);
    const float fac = fast_exp2(m_r - mn);
    m_r = mn;

    float psum = 0.f;
    u32 pk[4][2];
#pragma unroll
    for (int g = 0; g < 4; ++g) {
      const float e0 = fast_exp2(sacc[g][0] - mn);
      const float e1 = fast_exp2(sacc[g][1] - mn);
      const float e2 = fast_exp2(sacc[g][2] - mn);
      const float e3 = fast_exp2(sacc[g][3] - mn);
      psum += (e0 + e1) + (e2 + e3);
      pk[g][0] = cvt_pk_bf16(e0, e1);
      pk[g][1] = cvt_pk_bf16(e2, e3);
    }
    psum += __shfl_xor(psum, 16);
    psum += __shfl_xor(psum, 32);
    l_r = l_r * fac + psum;

    // stage P^(this wave) [q=fr][key] swizzled; same-wave DS ops are ordered
#pragma unroll
    for (int g = 0; g < 4; ++g) {
      u32x2 w2;
      w2[0] = pk[g][0];
      w2[1] = pk[g][1];
      *(u32x2*)(pw + ((g * 32 + kg * 8) ^ swz)) = w2;
    }

    // rescale O (rows q=kg*4+r need fac from lane kg*4+r)
#pragma unroll
    for (int r = 0; r < 4; ++r) {
      const float fq = __shfl(fac, kg * 4 + r);
      oacc[0][r] *= fq;
      oacc[1][r] *= fq;
    }

    // O += P.V
#pragma unroll
    for (int ks = 0; ks < 2; ++ks) {
      const short8 pf = *(const short8*)(pw + ((ks * 64 + kg * 16) ^ swz));
      oacc[0] = __builtin_amdgcn_mfma_f32_16x16x32_bf16(pf, vf[ks][0], oacc[0], 0, 0, 0);
      oacc[1] = __builtin_amdgcn_mfma_f32_16x16x32_bf16(pf, vf[ks][1], oacc[1], 0, 0, 0);
    }
  }

#pragma unroll
  for (int r = 0; r < 4; ++r) {
    const float lq = __shfl(l_r, kg * 4 + r);
    const float inv = __builtin_amdgcn_rcpf(lq);
    const int qg = q0 + wave * 16 + kg * 4 + r;
    ao[(b * 1024 + qg) * 256 + h * 32 + fr] = f2bf(oacc[0][r] * inv);
    ao[(b * 1024 + qg) * 256 + h * 32 + 16 + fr] = f2bf(oacc[1][r] * inv);
  }
}

extern "C" void kernel_launch(void* const* d_in, const int* in_sizes, int n_in,
                              void* d_out, int out_size, void* d_ws, size_t ws_size,
                              hipStream_t stream) {
  (void)in_sizes; (void)n_in; (void)out_size; (void)ws_size;
  const float* x    = (const float*)d_in[0];
  const float* Wq   = (const float*)d_in[1];
  const float* bq   = (const float*)d_in[2];
  const float* Wk   = (const float*)d_in[3];
  const float* bk   = (const float*)d_in[4];
  const float* Wv   = (const float*)d_in[5];
  const float* bv   = (const float*)d_in[6];
  const float* Wo   = (const float*)d_in[7];
  const float* bo   = (const float*)d_in[8];
  const float* btab = (const float*)d_in[9];
  // d_in[10] (rel_index) unused: recomputed analytically in-kernel.
  float* out = (float*)d_out;
  char* ws = (char*)d_ws;

  u16* xbf  = (u16*)(ws + 0);          // also attn_out after rel_attn_k
  u16* Wcat = (u16*)(ws + 8388608);
  u16* qbuf = (u16*)(ws + 8912896);
  u16* kbuf = (u16*)(ws + 17301504);
  u16* vtb  = (u16*)(ws + 25690112);

  cast_x_k<<<4096, 256, 0, stream>>>((const float4*)x, (u16x4*)xbf, 1048576);
  cast_w_k<<<256, 256, 0, stream>>>(Wq, Wk, Wv, Wo, (u16x4*)Wcat);
  proj_gemm_k<0><<<768, 256, 0, stream>>>(xbf, Wcat, bq, bk, bv, qbuf, kbuf, vtb, nullptr);
  rel_attn_k<<<2048, 256, 0, stream>>>(qbuf, kbuf, vtb, btab, xbf);
  proj_gemm_k<1><<<256, 256, 0, stream>>>(xbf, Wcat, bo, nullptr, nullptr,
                                          nullptr, nullptr, nullptr, out);
}

// Round 3
// 219.101 us; speedup vs baseline: 1.0211x; 1.0022x over previous
//
#include <hip/hip_runtime.h>

// RelativeMultiHeadAttention on MI355X (gfx950)
// cast_all -> proj_gemm<0> (QKV, 128x128, 2-phase dbuf LDS) ->
// rel_attn (flash, swapped-QK, dbuf K/V staging, 1 barrier/iter) -> proj_gemm<1>
// ws layout (bytes):
//   [0,          8388608)  x_bf16   [16384][256] bf16   (reused as attn_out)
//   [8388608,    8912896)  Wcat     [1024][256]  bf16   rows: Wq|Wk|Wv|Wo
//   [8912896,   17301504)  q_buf    [128][1024][32] bf16 (scale*log2e folded)
//   [17301504,  25690112)  k_buf    [128][1024][32] bf16
//   [25690112,  34078720)  v_t      [128][32][1024] bf16

typedef unsigned short u16;
typedef unsigned int u32;
typedef short short8 __attribute__((ext_vector_type(8)));
typedef u16 u16x4 __attribute__((ext_vector_type(4)));
typedef u32 u32x2 __attribute__((ext_vector_type(2)));
typedef float f32x4 __attribute__((ext_vector_type(4)));

#define NREL 3969
#define LOG2E 1.4426950408889634f
#define QS2 (0.17677669529663687f * 1.4426950408889634f)

__device__ __forceinline__ u16 f2bf(float f) {
  union { float f; unsigned u; } x; x.f = f;
  unsigned r = x.u + 0x7fffu + ((x.u >> 16) & 1u);
  return (u16)(r >> 16);
}

__device__ __forceinline__ u32 cvt_pk_bf16(float lo, float hi) {
  u32 r;
  asm("v_cvt_pk_bf16_f32 %0, %1, %2" : "=v"(r) : "v"(lo), "v"(hi));
  return r;
}

__device__ __forceinline__ float fast_exp2(float x) {
  float r;
  asm("v_exp_f32 %0, %1" : "=v"(r) : "v"(x));
  return r;
}

__device__ __forceinline__ void glds16(const u16* g, u16* l) {
  __builtin_amdgcn_global_load_lds((const __attribute__((address_space(1))) u32*)g,
                                   (__attribute__((address_space(3))) u32*)l, 16, 0, 0);
}

// x (1048576 float4) then Wq|Wk|Wv|Wo (65536 float4) -> bf16
__global__ __launch_bounds__(256) void cast_all_k(
    const float4* __restrict__ x,
    const float* __restrict__ wq, const float* __restrict__ wk,
    const float* __restrict__ wv, const float* __restrict__ wo,
    u16x4* __restrict__ xout, u16x4* __restrict__ wout) {
  int i = blockIdx.x * 256 + threadIdx.x;
  float4 v;
  u16x4* dst;
  if (i < 1048576) {
    v = x[i];
    dst = xout + i;
  } else {
    int wf = i - 1048576;
    int wi = wf >> 14, off = wf & 16383;
    const float* src = (wi == 0) ? wq : (wi == 1) ? wk : (wi == 2) ? wv : wo;
    v = ((const float4*)src)[off];
    dst = wout + wf;
  }
  u16x4 o;
  o[0] = f2bf(v.x); o[1] = f2bf(v.y); o[2] = f2bf(v.z); o[3] = f2bf(v.w);
  *dst = o;
}

// 128x128 tile, 4 waves (2x2 of 64x64), BK=32, 2-phase double-buffered staging.
// MODE 0: A=x_bf16, Wcat rows 0..767 -> q(scaled)/k/v_t.  MODE 1: rows 768..1023 -> f32 out.
// q/k and MODE1 use transposed MFMA (lane owns 4 consecutive n) for vector stores.
template <int MODE>
__global__ __launch_bounds__(256, 4) void proj_gemm_k(
    const u16* __restrict__ A, const u16* __restrict__ Wc,
    const float* __restrict__ b0, const float* __restrict__ b1,
    const float* __restrict__ b2,
    u16* __restrict__ qb, u16* __restrict__ kb, u16* __restrict__ vtb,
    float* __restrict__ outp) {
  const int NT = (MODE == 0) ? 6 : 2;
  const int m0 = (blockIdx.x / NT) * 128;
  const int n0 = (blockIdx.x % NT) * 128;
  const int wrow0 = (MODE == 0) ? n0 : (768 + n0);
  __shared__ u16 SH[16384];  // [A0 8KB][B0 8KB][A1 8KB][B1 8KB]
  const int tid = threadIdx.x;
  const int wave = tid >> 6, lane = tid & 63;
  const int fr = lane & 15, kg = lane >> 4;
  const int wm = wave >> 1, wn = wave & 1;
  const int l2 = lane >> 2;
  const int sseg = ((lane & 3) ^ (l2 & 3)) * 8;   // pre-swizzled source col (u16)
  const int r0 = wave * 16 + l2;
  const u16* gA = A + (m0 + r0) * 256 + sseg;
  const u16* gB = Wc + (wrow0 + r0) * 256 + sseg;
  const int dstw = wave * 1024;                    // byte offset within region
  const int rsw = (kg * 16) ^ ((fr & 3) << 4);

  f32x4 acc[4][4];
#pragma unroll
  for (int i = 0; i < 4; ++i)
#pragma unroll
    for (int j = 0; j < 4; ++j) acc[i][j] = (f32x4){0.f, 0.f, 0.f, 0.f};

  const int ws = (MODE == 0) ? ((n0 + wn * 64) >> 8) : 0;
  const bool vm = (MODE == 0) && (ws == 2);  // v keeps m-major acc

  // prologue stage (k0 = 0) into buf 0
  glds16(gA, (u16*)((char*)SH + dstw));
  glds16(gA + 64 * 256, (u16*)((char*)SH + 4096 + dstw));
  glds16(gB, (u16*)((char*)SH + 8192 + dstw));
  glds16(gB + 64 * 256, (u16*)((char*)SH + 12288 + dstw));
  __syncthreads();

  for (int it = 0; it < 8; ++it) {
    const int cur = it & 1;
    if (it < 7) {
      const int nb = 16384 * (cur ^ 1);
      const int ko = (it + 1) * 32;
      glds16(gA + ko, (u16*)((char*)SH + nb + dstw));
      glds16(gA + 64 * 256 + ko, (u16*)((char*)SH + nb + 4096 + dstw));
      glds16(gB + ko, (u16*)((char*)SH + nb + 8192 + dstw));
      glds16(gB + 64 * 256 + ko, (u16*)((char*)SH + nb + 12288 + dstw));
    }
    const char* abase = (const char*)SH + cur * 16384;
    const char* bbase = abase + 8192;
    short8 af[4], bf[4];
#pragma unroll
    for (int i = 0; i < 4; ++i) {
      af[i] = *(const short8*)(abase + (wm * 64 + i * 16 + fr) * 64 + rsw);
      bf[i] = *(const short8*)(bbase + (wn * 64 + i * 16 + fr) * 64 + rsw);
    }
    if (vm) {
#pragma unroll
      for (int mi = 0; mi < 4; ++mi)
#pragma unroll
        for (int ni = 0; ni < 4; ++ni)
          acc[mi][ni] = __builtin_amdgcn_mfma_f32_16x16x32_bf16(af[mi], bf[ni], acc[mi][ni], 0, 0, 0);
    } else {
#pragma unroll
      for (int mi = 0; mi < 4; ++mi)
#pragma unroll
        for (int ni = 0; ni < 4; ++ni)
          acc[mi][ni] = __builtin_amdgcn_mfma_f32_16x16x32_bf16(bf[ni], af[mi], acc[mi][ni], 0, 0, 0);
    }
    __syncthreads();
  }

  const int bI = m0 >> 10;
  if (MODE == 0) {
    const int nbb = (n0 + wn * 64) & 255;
    if (vm) {
      // v: lane owns 4 consecutive s for fixed (h,d)
#pragma unroll
      for (int ni = 0; ni < 4; ++ni) {
        const int nb = nbb + ni * 16 + fr;
        const int hh = nb >> 5, dd = nb & 31;
        const float bias = b2[nb];
#pragma unroll
        for (int mi = 0; mi < 4; ++mi) {
          const int s = (m0 & 1023) + wm * 64 + mi * 16 + kg * 4;
          u16x4 pk;
#pragma unroll
          for (int r = 0; r < 4; ++r) pk[r] = f2bf(acc[mi][ni][r] + bias);
          *(u16x4*)(vtb + ((bI * 8 + hh) * 32 + dd) * 1024 + s) = pk;
        }
      }
    } else {
      // q/k: transposed acc, lane owns 4 consecutive d for fixed s
      const float* bp = (ws == 0) ? b0 : b1;
      u16* dst = (ws == 0) ? qb : kb;
      const float sc = (ws == 0) ? QS2 : 1.0f;
#pragma unroll
      for (int ni = 0; ni < 4; ++ni) {
        const int nb4 = nbb + ni * 16 + kg * 4;
        const int hh = nb4 >> 5, d0 = nb4 & 31;
        const float4 b4 = *(const float4*)(bp + nb4);
#pragma unroll
        for (int mi = 0; mi < 4; ++mi) {
          const int s = (m0 & 1023) + wm * 64 + mi * 16 + fr;
          u16x4 pk;
#pragma unroll
          for (int r = 0; r < 4; ++r) pk[r] = f2bf((acc[mi][ni][r] + b4[r]) * sc);
          *(u16x4*)(dst + ((bI * 8 + hh) * 1024 + s) * 32 + d0) = pk;
        }
      }
    }
  } else {
#pragma unroll
    for (int ni = 0; ni < 4; ++ni) {
      const int n4 = n0 + wn * 64 + ni * 16 + kg * 4;
      const float4 b4 = *(const float4*)(b0 + n4);
#pragma unroll
      for (int mi = 0; mi < 4; ++mi) {
        const int m = m0 + wm * 64 + mi * 16 + fr;
        float4 o;
#pragma unroll
        for (int r = 0; r < 4; ++r) o[r] = acc[mi][ni][r] + b4[r];
        *(float4*)(outp + m * 256 + n4) = o;
      }
    }
  }
}

// Flash attention, swapped QK^T (lane owns one q-row), double-buffered K/V LDS
// staging via global_load_lds, one barrier per k-tile.
// grid: 2048 blocks (XCD-chunked), 4 waves, wave owns 16 q-rows.
__global__ __launch_bounds__(256, 4) void rel_attn_k(
    const u16* __restrict__ qb, const u16* __restrict__ kb,
    const u16* __restrict__ vtb, const float* __restrict__ btab,
    u16* __restrict__ ao) {
  const int bid0 = blockIdx.x;
  const int lid = (bid0 & 7) * 256 + (bid0 >> 3);  // XCD chunking: same bh -> same XCD
  const int bh = lid >> 4, qt = lid & 15;
  const int h = bh & 7, b = bh >> 3;
  const int q0 = qt * 64;
  __shared__ float bias_l[NREL];
  __shared__ u16 Kl[2][2048];    // [key 64][dk 32] rows 64B, src-preswizzled (2-bit)
  __shared__ u16 Vl[2][2048];    // [d 32][key 64] rows 128B, src-preswizzled (3-bit)
  __shared__ u16 Pl[4][1024];    // per-wave P tile [q 16][key 64], 128B rows, swizzled
  __shared__ __align__(16) float facl[4][16];
  const int tid = threadIdx.x;
  const int wave = tid >> 6, lane = tid & 63;
  const int fr = lane & 15, kg = lane >> 4;

  for (int i = tid; i < NREL; i += 256) bias_l[i] = btab[h * NREL + i] * LOG2E;

  const int krow = tid >> 2;
  const u16* kgsrc = kb + (bh * 1024 + krow) * 32 + ((tid & 3) ^ (krow & 3)) * 8;
  const int vrow = tid >> 3;
  const u16* vgsrc = vtb + (bh * 32 + vrow) * 1024 + ((tid & 7) ^ (vrow & 7)) * 8;
  u16* kld = &Kl[0][0] + wave * 512;
  u16* vld = &Vl[0][0] + wave * 512;

  const int q = q0 + wave * 16 + fr;
  const short8 qf = *(const short8*)(qb + (bh * 1024 + q) * 32 + kg * 8);
  const int qbase = (q >> 5) * 63 + (q & 31) + 1984;
  char* pw = (char*)Pl[wave] + fr * 128;
  const int swz = (fr & 7) << 4;
  float* facw = facl[wave];

  float m_r = -1e30f, l_r = 0.f;
  f32x4 oacc[2];
  oacc[0] = (f32x4){0.f, 0.f, 0.f, 0.f};
  oacc[1] = (f32x4){0.f, 0.f, 0.f, 0.f};

  glds16(kgsrc, kld);
  glds16(vgsrc, vld);
  __syncthreads();  // bias_l ready + buf0 staged (barrier drains vmcnt)

  for (int kt = 0; kt < 16; ++kt) {
    const int cur = kt & 1;
    if (kt < 15) {
      glds16(kgsrc + (kt + 1) * 2048, kld + (cur ^ 1) * 2048);
      glds16(vgsrc + (kt + 1) * 64, vld + (cur ^ 1) * 2048);
    }
    const char* kbase = (const char*)Kl[cur];
    const char* vbase = (const char*)Vl[cur];
    short8 kf[4], vf[2][2];
#pragma unroll
    for (int g = 0; g < 4; ++g)
      kf[g] = *(const short8*)(kbase + (g * 16 + fr) * 64 + ((kg * 16) ^ ((fr & 3) << 4)));
#pragma unroll
    for (int ks = 0; ks < 2; ++ks)
#pragma unroll
      for (int g2 = 0; g2 < 2; ++g2)
        vf[ks][g2] = *(const short8*)(vbase + (g2 * 16 + fr) * 128 + (((ks * 4 + kg) << 4) ^ swz));

    // S^T = K.Q (row=key, col=q=fr); scale*log2e folded into q
    f32x4 sacc[4];
#pragma unroll
    for (int g = 0; g < 4; ++g)
      sacc[g] = __builtin_amdgcn_mfma_f32_16x16x32_bf16(kf[g], qf, (f32x4){0.f, 0.f, 0.f, 0.f}, 0, 0, 0);

    // + bias (analytic): idx = qbase - key - 31*ki
    const int t0 = qbase - kt * 126 - kg * 4;
    float mloc = -1e30f;
#pragma unroll
    for (int g = 0; g < 4; ++g) {
      const int ag = t0 - g * 16 - 31 * (g >> 1);
#pragma unroll
      for (int r = 0; r < 4; ++r) {
        const float v = sacc[g][r] + bias_l[ag - r];
        sacc[g][r] = v;
        mloc = fmaxf(mloc, v);
      }
    }
    mloc = fmaxf(mloc, __shfl_xor(mloc, 16));
    mloc = fmaxf(mloc, __shfl_xor(mloc, 32));
    const float mn = fmaxf(m_r, mloc);
    const float fac = fast_exp2(m_r - mn);
    m_r = mn;
    if (kg == 0) facw[fr] = fac;   // broadcast fac per q-row via LDS

    float psum = 0.f;
    u32 pk[4][2];
#pragma unroll
    for (int g = 0; g < 4; ++g) {
      const float e0 = fast_exp2(sacc[g][0] - mn);
      const float e1 = fast_exp2(sacc[g][1] - mn);
      const float e2 = fast_exp2(sacc[g][2] - mn);
      const float e3 = fast_exp2(sacc[g][3] - mn);
      psum += (e0 + e1) + (e2 + e3);
      pk[g][0] = cvt_pk_bf16(e0, e1);
      pk[g][1] = cvt_pk_bf16(e2, e3);
    }
    psum += __shfl_xor(psum, 16);
    psum += __shfl_xor(psum, 32);
    l_r = l_r * fac + psum;

    // stage P (same-wave DS ops are ordered; no barrier)
#pragma unroll
    for (int g = 0; g < 4; ++g) {
      u32x2 w2;
      w2[0] = pk[g][0];
      w2[1] = pk[g][1];
      *(u32x2*)(pw + ((g * 32 + kg * 8) ^ swz)) = w2;
    }

    const float4 fv = *(const float4*)&facw[kg * 4];
#pragma unroll
    for (int r = 0; r < 4; ++r) {
      oacc[0][r] *= fv[r];
      oacc[1][r] *= fv[r];
    }

    // O += P.V
#pragma unroll
    for (int ks = 0; ks < 2; ++ks) {
      const short8 pf = *(const short8*)(pw + ((ks * 64 + kg * 16) ^ swz));
      oacc[0] = __builtin_amdgcn_mfma_f32_16x16x32_bf16(pf, vf[ks][0], oacc[0], 0, 0, 0);
      oacc[1] = __builtin_amdgcn_mfma_f32_16x16x32_bf16(pf, vf[ks][1], oacc[1], 0, 0, 0);
    }
    __syncthreads();
  }

  // epilogue: 1/l broadcast, restage O through Pl[wave], coalesced short8 stores
  if (kg == 0) facw[fr] = __builtin_amdgcn_rcpf(l_r);
  const float4 lv = *(const float4*)&facw[kg * 4];
#pragma unroll
  for (int g2 = 0; g2 < 2; ++g2)
#pragma unroll
    for (int r = 0; r < 4; ++r)
      *(u16*)((char*)Pl[wave] + (kg * 4 + r) * 64 + (g2 * 16 + fr) * 2) =
          f2bf(oacc[g2][r] * lv[r]);
  const int orow = lane >> 2, oseg = lane & 3;
  const short8 ov = *(const short8*)((char*)Pl[wave] + orow * 64 + oseg * 16);
  *(short8*)(ao + (b * 1024 + q0 + wave * 16 + orow) * 256 + h * 32 + oseg * 8) = ov;
}

extern "C" void kernel_launch(void* const* d_in, const int* in_sizes, int n_in,
                              void* d_out, int out_size, void* d_ws, size_t ws_size,
                              hipStream_t stream) {
  (void)in_sizes; (void)n_in; (void)out_size; (void)ws_size;
  const float* x    = (const float*)d_in[0];
  const float* Wq   = (const float*)d_in[1];
  const float* bq   = (const float*)d_in[2];
  const float* Wk   = (const float*)d_in[3];
  const float* bk   = (const float*)d_in[4];
  const float* Wv   = (const float*)d_in[5];
  const float* bv   = (const float*)d_in[6];
  const float* Wo   = (const float*)d_in[7];
  const float* bo   = (const float*)d_in[8];
  const float* btab = (const float*)d_in[9];
  // d_in[10] (rel_index) unused: recomputed analytically in-kernel.
  float* out = (float*)d_out;
  char* ws = (char*)d_ws;

  u16* xbf  = (u16*)(ws + 0);          // also attn_out after rel_attn_k
  u16* Wcat = (u16*)(ws + 8388608);
  u16* qbuf = (u16*)(ws + 8912896);
  u16* kbuf = (u16*)(ws + 17301504);
  u16* vtb  = (u16*)(ws + 25690112);

  cast_all_k<<<4352, 256, 0, stream>>>((const float4*)x, Wq, Wk, Wv, Wo,
                                       (u16x4*)xbf, (u16x4*)Wcat);
  proj_gemm_k<0><<<768, 256, 0, stream>>>(xbf, Wcat, bq, bk, bv, qbuf, kbuf, vtb, nullptr);
  rel_attn_k<<<2048, 256, 0, stream>>>(qbuf, kbuf, vtb, btab, xbf);
  proj_gemm_k<1><<<256, 256, 0, stream>>>(xbf, Wcat, bo, nullptr, nullptr,
                                          nullptr, nullptr, nullptr, out);
}

// Round 4
// 206.853 us; speedup vs baseline: 1.0815x; 1.0592x over previous
//
#include <hip/hip_runtime.h>

// RelativeMultiHeadAttention on MI355X (gfx950)
// cast_all -> proj_gemm<0> (QKV, 128x128, dbuf, XCD-chunked, LDS-restaged epilogue) ->
// rel_attn (flash, swapped-QK, dbuf K/V staging) -> proj_gemm<1> (out+bias)
// ws layout (bytes):
//   [0,          8388608)  x_bf16   [16384][256] bf16   (reused as attn_out)
//   [8388608,    8912896)  Wcat     [1024][256]  bf16   rows: Wq|Wk|Wv|Wo
//   [8912896,   17301504)  q_buf    [128][1024][32] bf16 (scale*log2e folded)
//   [17301504,  25690112)  k_buf    [128][1024][32] bf16
//   [25690112,  34078720)  v_t      [128][32][1024] bf16

typedef unsigned short u16;
typedef unsigned int u32;
typedef short short8 __attribute__((ext_vector_type(8)));
typedef u16 u16x4 __attribute__((ext_vector_type(4)));
typedef u32 u32x2 __attribute__((ext_vector_type(2)));
typedef float f32x4 __attribute__((ext_vector_type(4)));

#define NREL 3969
#define LOG2E 1.4426950408889634f
#define QS2 (0.17677669529663687f * 1.4426950408889634f)

__device__ __forceinline__ u16 f2bf(float f) {
  union { float f; unsigned u; } x; x.f = f;
  unsigned r = x.u + 0x7fffu + ((x.u >> 16) & 1u);
  return (u16)(r >> 16);
}

__device__ __forceinline__ u32 cvt_pk_bf16(float lo, float hi) {
  u32 r;
  asm("v_cvt_pk_bf16_f32 %0, %1, %2" : "=v"(r) : "v"(lo), "v"(hi));
  return r;
}

__device__ __forceinline__ float fast_exp2(float x) {
  float r;
  asm("v_exp_f32 %0, %1" : "=v"(r) : "v"(x));
  return r;
}

__device__ __forceinline__ void glds16(const u16* g, u16* l) {
  __builtin_amdgcn_global_load_lds((const __attribute__((address_space(1))) u32*)g,
                                   (__attribute__((address_space(3))) u32*)l, 16, 0, 0);
}

// x (1048576 float4) then Wq|Wk|Wv|Wo (65536 float4) -> bf16
__global__ __launch_bounds__(256) void cast_all_k(
    const float4* __restrict__ x,
    const float* __restrict__ wq, const float* __restrict__ wk,
    const float* __restrict__ wv, const float* __restrict__ wo,
    u16x4* __restrict__ xout, u16x4* __restrict__ wout) {
  int i = blockIdx.x * 256 + threadIdx.x;
  float4 v;
  u16x4* dst;
  if (i < 1048576) {
    v = x[i];
    dst = xout + i;
  } else {
    int wf = i - 1048576;
    int wi = wf >> 14, off = wf & 16383;
    const float* src = (wi == 0) ? wq : (wi == 1) ? wk : (wi == 2) ? wv : wo;
    v = ((const float4*)src)[off];
    dst = wout + wf;
  }
  u16x4 o;
  o[0] = f2bf(v.x); o[1] = f2bf(v.y); o[2] = f2bf(v.z); o[3] = f2bf(v.w);
  *dst = o;
}

// 128x128 tile, 4 waves (2x2 of 64x64), BK=32, 2-phase dbuf, XCD-chunked blockIdx.
// MODE 0: A=x_bf16, Wcat rows 0..767 -> q(scaled)/k/v_t, epilogue restaged via LDS.
// MODE 1: rows 768..1023 -> f32 out (+bo), direct 64B-line stores.
template <int MODE>
__global__ __launch_bounds__(256, 4) void proj_gemm_k(
    const u16* __restrict__ A, const u16* __restrict__ Wc,
    const float* __restrict__ b0, const float* __restrict__ b1,
    const float* __restrict__ b2,
    u16* __restrict__ qb, u16* __restrict__ kb, u16* __restrict__ vtb,
    float* __restrict__ outp) {
  const int NT = (MODE == 0) ? 6 : 2;
  const int NWG8 = (MODE == 0) ? 96 : 32;
  const int lid = (blockIdx.x & 7) * NWG8 + (blockIdx.x >> 3);  // XCD-chunked
  const int m0 = (lid / NT) * 128;
  const int n0 = (lid % NT) * 128;
  const int wrow0 = (MODE == 0) ? n0 : (768 + n0);
  __shared__ u16 SH[16384];  // dbuf: [A0 8KB][B0 8KB][A1 8KB][B1 8KB]; epilogue: 4x8KB
  const int tid = threadIdx.x;
  const int wave = tid >> 6, lane = tid & 63;
  const int fr = lane & 15, kg = lane >> 4;
  const int wm = wave >> 1, wn = wave & 1;
  const int l2 = lane >> 2;
  const int sseg = ((lane & 3) ^ (l2 & 3)) * 8;   // pre-swizzled source col (u16)
  const int r0 = wave * 16 + l2;
  const u16* gA = A + (m0 + r0) * 256 + sseg;
  const u16* gB = Wc + (wrow0 + r0) * 256 + sseg;
  const int dstw = wave * 1024;                    // byte offset within region
  const int rsw = (kg * 16) ^ ((fr & 3) << 4);

  f32x4 acc[4][4];
#pragma unroll
  for (int i = 0; i < 4; ++i)
#pragma unroll
    for (int j = 0; j < 4; ++j) acc[i][j] = (f32x4){0.f, 0.f, 0.f, 0.f};

  const int ws = (MODE == 0) ? ((n0 + wn * 64) >> 8) : 0;
  const bool vm = (MODE == 0) && (ws == 2);  // v keeps m-major acc

  glds16(gA, (u16*)((char*)SH + dstw));
  glds16(gA + 64 * 256, (u16*)((char*)SH + 4096 + dstw));
  glds16(gB, (u16*)((char*)SH + 8192 + dstw));
  glds16(gB + 64 * 256, (u16*)((char*)SH + 12288 + dstw));
  __syncthreads();

  for (int it = 0; it < 8; ++it) {
    const int cur = it & 1;
    if (it < 7) {
      const int nb = 16384 * (cur ^ 1);
      const int ko = (it + 1) * 32;
      glds16(gA + ko, (u16*)((char*)SH + nb + dstw));
      glds16(gA + 64 * 256 + ko, (u16*)((char*)SH + nb + 4096 + dstw));
      glds16(gB + ko, (u16*)((char*)SH + nb + 8192 + dstw));
      glds16(gB + 64 * 256 + ko, (u16*)((char*)SH + nb + 12288 + dstw));
    }
    const char* abase = (const char*)SH + cur * 16384;
    const char* bbase = abase + 8192;
    short8 af[4], bf[4];
#pragma unroll
    for (int i = 0; i < 4; ++i) {
      af[i] = *(const short8*)(abase + (wm * 64 + i * 16 + fr) * 64 + rsw);
      bf[i] = *(const short8*)(bbase + (wn * 64 + i * 16 + fr) * 64 + rsw);
    }
    if (vm) {
#pragma unroll
      for (int mi = 0; mi < 4; ++mi)
#pragma unroll
        for (int ni = 0; ni < 4; ++ni)
          acc[mi][ni] = __builtin_amdgcn_mfma_f32_16x16x32_bf16(af[mi], bf[ni], acc[mi][ni], 0, 0, 0);
    } else {
#pragma unroll
      for (int mi = 0; mi < 4; ++mi)
#pragma unroll
        for (int ni = 0; ni < 4; ++ni)
          acc[mi][ni] = __builtin_amdgcn_mfma_f32_16x16x32_bf16(bf[ni], af[mi], acc[mi][ni], 0, 0, 0);
    }
    __syncthreads();
  }

  const int bI = m0 >> 10;
  const int s0 = (m0 & 1023) + wm * 64;
  if (MODE == 0) {
    const int nbb = (n0 + wn * 64) & 255;   // col base within tensor (0..255)
    char* shw = (char*)SH + wave * 8192;    // per-wave 8KB restage region
    if (vm) {
      // restage as [n_local 64][s 64] u16 (128B rows, XOR-swizzled)
#pragma unroll
      for (int ni = 0; ni < 4; ++ni) {
        const int nl = ni * 16 + fr;
        const float bias = b2[nbb + nl];
#pragma unroll
        for (int mi = 0; mi < 4; ++mi) {
          u16x4 pk;
#pragma unroll
          for (int r = 0; r < 4; ++r) pk[r] = f2bf(acc[mi][ni][r] + bias);
          *(u16x4*)(shw + nl * 128 + (((mi * 16 + kg * 4) * 2) ^ ((nl & 7) << 4))) = pk;
        }
      }
      // write back: 8 instrs, each 8 n-rows x 128B contiguous
      const int l8 = lane >> 3, seg8 = lane & 7;
#pragma unroll
      for (int i = 0; i < 8; ++i) {
        const int nl = i * 8 + l8;
        const short8 val = *(const short8*)(shw + nl * 128 + ((seg8 * 16) ^ ((nl & 7) << 4)));
        const int hg = (nbb >> 5) + (nl >> 5), dd = nl & 31;
        *(short8*)(vtb + ((bI * 8 + hg) * 32 + dd) * 1024 + s0 + seg8 * 8) = val;
      }
    } else {
      // q/k (transposed acc): restage as [s_local 64][n 64] u16
      const float* bp = (ws == 0) ? b0 : b1;
      u16* dst = (ws == 0) ? qb : kb;
      const float sc = (ws == 0) ? QS2 : 1.0f;
#pragma unroll
      for (int ni = 0; ni < 4; ++ni) {
        const float4 b4 = *(const float4*)(bp + nbb + ni * 16 + kg * 4);
#pragma unroll
        for (int mi = 0; mi < 4; ++mi) {
          const int sl = mi * 16 + fr;
          u16x4 pk;
#pragma unroll
          for (int r = 0; r < 4; ++r) pk[r] = f2bf((acc[mi][ni][r] + b4[r]) * sc);
          *(u16x4*)(shw + sl * 128 + (((ni * 32 + kg * 8)) ^ ((sl & 7) << 4))) = pk;
        }
      }
      // write back: 8 instrs (2 heads x 4 groups), each 1KB contiguous
      const int l4 = lane >> 2, seg = lane & 3;
#pragma unroll
      for (int hh = 0; hh < 2; ++hh) {
#pragma unroll
        for (int g = 0; g < 4; ++g) {
          const int sl = g * 16 + l4;
          const short8 val = *(const short8*)(shw + sl * 128 + ((hh * 64 + seg * 16) ^ ((sl & 7) << 4)));
          const int hg = (nbb >> 5) + hh;
          *(short8*)(dst + ((bI * 8 + hg) * 1024 + s0 + sl) * 32 + seg * 8) = val;
        }
      }
    }
  } else {
#pragma unroll
    for (int ni = 0; ni < 4; ++ni) {
      const int n4 = n0 + wn * 64 + ni * 16 + kg * 4;
      const float4 b4 = *(const float4*)(b0 + n4);
#pragma unroll
      for (int mi = 0; mi < 4; ++mi) {
        const int m = m0 + wm * 64 + mi * 16 + fr;
        float4 o;
#pragma unroll
        for (int r = 0; r < 4; ++r) o[r] = acc[mi][ni][r] + b4[r];
        *(float4*)(outp + m * 256 + n4) = o;
      }
    }
  }
}

// Flash attention, swapped QK^T (lane owns one q-row), double-buffered K/V LDS
// staging via global_load_lds, one barrier per k-tile.
// grid: 2048 blocks (XCD-chunked), 4 waves, wave owns 16 q-rows.
__global__ __launch_bounds__(256, 4) void rel_attn_k(
    const u16* __restrict__ qb, const u16* __restrict__ kb,
    const u16* __restrict__ vtb, const float* __restrict__ btab,
    u16* __restrict__ ao) {
  const int bid0 = blockIdx.x;
  const int lid = (bid0 & 7) * 256 + (bid0 >> 3);  // XCD chunking: same bh -> same XCD
  const int bh = lid >> 4, qt = lid & 15;
  const int h = bh & 7, b = bh >> 3;
  const int q0 = qt * 64;
  __shared__ float bias_l[NREL];
  __shared__ u16 Kl[2][2048];    // [key 64][dk 32] rows 64B, src-preswizzled (2-bit)
  __shared__ u16 Vl[2][2048];    // [d 32][key 64] rows 128B, src-preswizzled (3-bit)
  __shared__ u16 Pl[4][1024];    // per-wave P tile [q 16][key 64], 128B rows, swizzled
  __shared__ __align__(16) float facl[4][16];
  const int tid = threadIdx.x;
  const int wave = tid >> 6, lane = tid & 63;
  const int fr = lane & 15, kg = lane >> 4;

  for (int i = tid; i < NREL; i += 256) bias_l[i] = btab[h * NREL + i] * LOG2E;

  const int krow = tid >> 2;
  const u16* kgsrc = kb + (bh * 1024 + krow) * 32 + ((tid & 3) ^ (krow & 3)) * 8;
  const int vrow = tid >> 3;
  const u16* vgsrc = vtb + (bh * 32 + vrow) * 1024 + ((tid & 7) ^ (vrow & 7)) * 8;
  u16* kld = &Kl[0][0] + wave * 512;
  u16* vld = &Vl[0][0] + wave * 512;

  const int q = q0 + wave * 16 + fr;
  const short8 qf = *(const short8*)(qb + (bh * 1024 + q) * 32 + kg * 8);
  const int qbase = (q >> 5) * 63 + (q & 31) + 1984;
  char* pw = (char*)Pl[wave] + fr * 128;
  const int swz = (fr & 7) << 4;
  float* facw = facl[wave];

  float m_r = -1e30f, l_r = 0.f;
  f32x4 oacc[2];
  oacc[0] = (f32x4){0.f, 0.f, 0.f, 0.f};
  oacc[1] = (f32x4){0.f, 0.f, 0.f, 0.f};

  glds16(kgsrc, kld);
  glds16(vgsrc, vld);
  __syncthreads();  // bias_l ready + buf0 staged (barrier drains vmcnt)

  for (int kt = 0; kt < 16; ++kt) {
    const int cur = kt & 1;
    if (kt < 15) {
      glds16(kgsrc + (kt + 1) * 2048, kld + (cur ^ 1) * 2048);
      glds16(vgsrc + (kt + 1) * 64, vld + (cur ^ 1) * 2048);
    }
    const char* kbase = (const char*)Kl[cur];
    const char* vbase = (const char*)Vl[cur];
    short8 kf[4], vf[2][2];
#pragma unroll
    for (int g = 0; g < 4; ++g)
      kf[g] = *(const short8*)(kbase + (g * 16 + fr) * 64 + ((kg * 16) ^ ((fr & 3) << 4)));
#pragma unroll
    for (int ks = 0; ks < 2; ++ks)
#pragma unroll
      for (int g2 = 0; g2 < 2; ++g2)
        vf[ks][g2] = *(const short8*)(vbase + (g2 * 16 + fr) * 128 + (((ks * 4 + kg) << 4) ^ swz));

    // S^T = K.Q (row=key, col=q=fr); scale*log2e folded into q
    f32x4 sacc[4];
    __builtin_amdgcn_s_setprio(1);
#pragma unroll
    for (int g = 0; g < 4; ++g)
      sacc[g] = __builtin_amdgcn_mfma_f32_16x16x32_bf16(kf[g], qf, (f32x4){0.f, 0.f, 0.f, 0.f}, 0, 0, 0);
    __builtin_amdgcn_s_setprio(0);

    // + bias (analytic): idx = qbase - key - 31*ki
    const int t0 = qbase - kt * 126 - kg * 4;
    float mloc = -1e30f;
#pragma unroll
    for (int g = 0; g < 4; ++g) {
      const int ag = t0 - g * 16 - 31 * (g >> 1);
#pragma unroll
      for (int r = 0; r < 4; ++r) {
        const float v = sacc[g][r] + bias_l[ag - r];
        sacc[g][r] = v;
        mloc = fmaxf(mloc, v);
      }
    }
    mloc = fmaxf(mloc, __shfl_xor(mloc, 16));
    mloc = fmaxf(mloc, __shfl_xor(mloc, 32));
    const float mn = fmaxf(m_r, mloc);
    const float fac = fast_exp2(m_r - mn);
    m_r = mn;
    if (kg == 0) facw[fr] = fac;   // broadcast fac per q-row via LDS

    float psum = 0.f;
    u32 pk[4][2];
#pragma unroll
    for (int g = 0; g < 4; ++g) {
      const float e0 = fast_exp2(sacc[g][0] - mn);
      const float e1 = fast_exp2(sacc[g][1] - mn);
      const float e2 = fast_exp2(sacc[g][2] - mn);
      const float e3 = fast_exp2(sacc[g][3] - mn);
      psum += (e0 + e1) + (e2 + e3);
      pk[g][0] = cvt_pk_bf16(e0, e1);
      pk[g][1] = cvt_pk_bf16(e2, e3);
    }
    psum += __shfl_xor(psum, 16);
    psum += __shfl_xor(psum, 32);
    l_r = l_r * fac + psum;

    // stage P (same-wave DS ops are ordered; no barrier)
#pragma unroll
    for (int g = 0; g < 4; ++g) {
      u32x2 w2;
      w2[0] = pk[g][0];
      w2[1] = pk[g][1];
      *(u32x2*)(pw + ((g * 32 + kg * 8) ^ swz)) = w2;
    }

    const float4 fv = *(const float4*)&facw[kg * 4];
#pragma unroll
    for (int r = 0; r < 4; ++r) {
      oacc[0][r] *= fv[r];
      oacc[1][r] *= fv[r];
    }

    // O += P.V
#pragma unroll
    for (int ks = 0; ks < 2; ++ks) {
      const short8 pf = *(const short8*)(pw + ((ks * 64 + kg * 16) ^ swz));
      __builtin_amdgcn_s_setprio(1);
      oacc[0] = __builtin_amdgcn_mfma_f32_16x16x32_bf16(pf, vf[ks][0], oacc[0], 0, 0, 0);
      oacc[1] = __builtin_amdgcn_mfma_f32_16x16x32_bf16(pf, vf[ks][1], oacc[1], 0, 0, 0);
      __builtin_amdgcn_s_setprio(0);
    }
    __syncthreads();
  }

  // epilogue: 1/l broadcast, restage O through Pl[wave], coalesced short8 stores
  if (kg == 0) facw[fr] = __builtin_amdgcn_rcpf(l_r);
  const float4 lv = *(const float4*)&facw[kg * 4];
#pragma unroll
  for (int g2 = 0; g2 < 2; ++g2)
#pragma unroll
    for (int r = 0; r < 4; ++r)
      *(u16*)((char*)Pl[wave] + (kg * 4 + r) * 64 + (g2 * 16 + fr) * 2) =
          f2bf(oacc[g2][r] * lv[r]);
  const int orow = lane >> 2, oseg = lane & 3;
  const short8 ov = *(const short8*)((char*)Pl[wave] + orow * 64 + oseg * 16);
  *(short8*)(ao + (b * 1024 + q0 + wave * 16 + orow) * 256 + h * 32 + oseg * 8) = ov;
}

extern "C" void kernel_launch(void* const* d_in, const int* in_sizes, int n_in,
                              void* d_out, int out_size, void* d_ws, size_t ws_size,
                              hipStream_t stream) {
  (void)in_sizes; (void)n_in; (void)out_size; (void)ws_size;
  const float* x    = (const float*)d_in[0];
  const float* Wq   = (const float*)d_in[1];
  const float* bq   = (const float*)d_in[2];
  const float* Wk   = (const float*)d_in[3];
  const float* bk   = (const float*)d_in[4];
  const float* Wv   = (const float*)d_in[5];
  const float* bv   = (const float*)d_in[6];
  const float* Wo   = (const float*)d_in[7];
  const float* bo   = (const float*)d_in[8];
  const float* btab = (const float*)d_in[9];
  // d_in[10] (rel_index) unused: recomputed analytically in-kernel.
  float* out = (float*)d_out;
  char* ws = (char*)d_ws;

  u16* xbf  = (u16*)(ws + 0);          // also attn_out after rel_attn_k
  u16* Wcat = (u16*)(ws + 8388608);
  u16* qbuf = (u16*)(ws + 8912896);
  u16* kbuf = (u16*)(ws + 17301504);
  u16* vtb  = (u16*)(ws + 25690112);

  cast_all_k<<<4352, 256, 0, stream>>>((const float4*)x, Wq, Wk, Wv, Wo,
                                       (u16x4*)xbf, (u16x4*)Wcat);
  proj_gemm_k<0><<<768, 256, 0, stream>>>(xbf, Wcat, bq, bk, bv, qbuf, kbuf, vtb, nullptr);
  rel_attn_k<<<2048, 256, 0, stream>>>(qbuf, kbuf, vtb, btab, xbf);
  proj_gemm_k<1><<<256, 256, 0, stream>>>(xbf, Wcat, bo, nullptr, nullptr,
                                          nullptr, nullptr, nullptr, out);
}

// Round 5
// 158.589 us; speedup vs baseline: 1.4107x; 1.3043x over previous
//
#include <hip/hip_runtime.h>

// RelativeMultiHeadAttention on MI355X (gfx950)
// cast_all -> proj_qkv (128x128, 3-stage counted-vmcnt pipeline) ->
// rel_attn (flash, swapped-QK, no-max exp2 softmax, ones-MFMA row sums) ->
// proj_out (64x128, 3-stage pipeline)
// ws layout (bytes):
//   [0,          8388608)  x_bf16   [16384][256] bf16   (reused as attn_out)
//   [8388608,    8912896)  Wcat     [1024][256]  bf16   rows: Wq|Wk|Wv|Wo
//   [8912896,   17301504)  q_buf    [128][1024][32] bf16 (scale*log2e folded)
//   [17301504,  25690112)  k_buf    [128][1024][32] bf16
//   [25690112,  34078720)  v_t      [128][32][1024] bf16

typedef unsigned short u16;
typedef unsigned int u32;
typedef short short8 __attribute__((ext_vector_type(8)));
typedef u16 u16x4 __attribute__((ext_vector_type(4)));
typedef u32 u32x2 __attribute__((ext_vector_type(2)));
typedef float f32x4 __attribute__((ext_vector_type(4)));

#define NREL 3969
#define LOG2E 1.4426950408889634f
#define QS2 (0.17677669529663687f * 1.4426950408889634f)

__device__ __forceinline__ u16 f2bf(float f) {
  union { float f; unsigned u; } x; x.f = f;
  unsigned r = x.u + 0x7fffu + ((x.u >> 16) & 1u);
  return (u16)(r >> 16);
}

__device__ __forceinline__ u32 cvt_pk_bf16(float lo, float hi) {
  u32 r;
  asm("v_cvt_pk_bf16_f32 %0, %1, %2" : "=v"(r) : "v"(lo), "v"(hi));
  return r;
}

__device__ __forceinline__ float fast_exp2(float x) {
  float r;
  asm("v_exp_f32 %0, %1" : "=v"(r) : "v"(x));
  return r;
}

__device__ __forceinline__ void glds16(const u16* g, u16* l) {
  __builtin_amdgcn_global_load_lds((const __attribute__((address_space(1))) u32*)g,
                                   (__attribute__((address_space(3))) u32*)l, 16, 0, 0);
}

template <int N> __device__ __forceinline__ void wait_vm() {
  asm volatile("s_waitcnt vmcnt(%0)" ::"n"(N) : "memory");
}

// x (1048576 float4) then Wq|Wk|Wv|Wo (65536 float4) -> bf16
__global__ __launch_bounds__(256) void cast_all_k(
    const float4* __restrict__ x,
    const float* __restrict__ wq, const float* __restrict__ wk,
    const float* __restrict__ wv, const float* __restrict__ wo,
    u16x4* __restrict__ xout, u16x4* __restrict__ wout) {
  int i = blockIdx.x * 256 + threadIdx.x;
  float4 v;
  u16x4* dst;
  if (i < 1048576) {
    v = x[i];
    dst = xout + i;
  } else {
    int wf = i - 1048576;
    int wi = wf >> 14, off = wf & 16383;
    const float* src = (wi == 0) ? wq : (wi == 1) ? wk : (wi == 2) ? wv : wo;
    v = ((const float4*)src)[off];
    dst = wout + wf;
  }
  u16x4 o;
  o[0] = f2bf(v.x); o[1] = f2bf(v.y); o[2] = f2bf(v.z); o[3] = f2bf(v.w);
  *dst = o;
}

// QKV projection: 128x128 tile, 4 waves (2x2 of 64x64), BK=32, 3-stage pipeline,
// counted vmcnt (never drains to 0 in-loop), XCD-chunked blockIdx, LDS-restaged epilogue.
__global__ __launch_bounds__(256, 3) void proj_qkv_k(
    const u16* __restrict__ A, const u16* __restrict__ Wc,
    const float* __restrict__ b0, const float* __restrict__ b1,
    const float* __restrict__ b2,
    u16* __restrict__ qb, u16* __restrict__ kb, u16* __restrict__ vtb) {
  const int lid = (blockIdx.x & 7) * 96 + (blockIdx.x >> 3);  // 768 = 8*96 bijective
  const int m0 = (lid / 6) * 128;
  const int n0 = (lid % 6) * 128;
  __shared__ u16 SH[24576];  // 48KB = 3 stages x [A 8KB][B 8KB]
  const int tid = threadIdx.x;
  const int wave = tid >> 6, lane = tid & 63;
  const int fr = lane & 15, kg = lane >> 4;
  const int wm = wave >> 1, wn = wave & 1;
  const int l2 = lane >> 2;
  const int sseg = ((lane & 3) ^ (l2 & 3)) * 8;   // pre-swizzled source col (u16)
  const u16* gA = A + (m0 + wave * 16 + l2) * 256 + sseg;
  const u16* gB = Wc + (n0 + wave * 16 + l2) * 256 + sseg;
  const int dstw = wave * 1024;  // byte offset within 4KB half-region
  const int rsw = (kg * 16) ^ ((fr & 3) << 4);

  f32x4 acc[4][4];
#pragma unroll
  for (int i = 0; i < 4; ++i)
#pragma unroll
    for (int j = 0; j < 4; ++j) acc[i][j] = (f32x4){0.f, 0.f, 0.f, 0.f};

  const int ws = (n0 + wn * 64) >> 8;  // 0=q 1=k 2=v, uniform per wave
  const bool vm = (ws == 2);

#define PSTG(t, sb)                                                     \
  do {                                                                  \
    glds16(gA + (t) * 32,         (u16*)((char*)SH + (sb) + dstw));     \
    glds16(gA + 16384 + (t) * 32, (u16*)((char*)SH + (sb) + 4096 + dstw)); \
    glds16(gB + (t) * 32,         (u16*)((char*)SH + (sb) + 8192 + dstw)); \
    glds16(gB + 16384 + (t) * 32, (u16*)((char*)SH + (sb) + 12288 + dstw)); \
  } while (0)

  PSTG(0, 0);
  PSTG(1, 16384);
#pragma unroll
  for (int it = 0; it < 8; ++it) {
    if (it < 6) PSTG(it + 2, ((it + 2) % 3) * 16384);
    if (it < 6) wait_vm<8>();
    else if (it == 6) wait_vm<4>();
    else wait_vm<0>();
    __builtin_amdgcn_s_barrier();
    const char* abase = (const char*)SH + (it % 3) * 16384;
    const char* bbase = abase + 8192;
    short8 af[4], bf[4];
#pragma unroll
    for (int i = 0; i < 4; ++i) {
      af[i] = *(const short8*)(abase + (wm * 64 + i * 16 + fr) * 64 + rsw);
      bf[i] = *(const short8*)(bbase + (wn * 64 + i * 16 + fr) * 64 + rsw);
    }
    if (vm) {
#pragma unroll
      for (int mi = 0; mi < 4; ++mi)
#pragma unroll
        for (int ni = 0; ni < 4; ++ni)
          acc[mi][ni] = __builtin_amdgcn_mfma_f32_16x16x32_bf16(af[mi], bf[ni], acc[mi][ni], 0, 0, 0);
    } else {
#pragma unroll
      for (int mi = 0; mi < 4; ++mi)
#pragma unroll
        for (int ni = 0; ni < 4; ++ni)
          acc[mi][ni] = __builtin_amdgcn_mfma_f32_16x16x32_bf16(bf[ni], af[mi], acc[mi][ni], 0, 0, 0);
    }
    __builtin_amdgcn_s_barrier();
  }
#undef PSTG

  const int bI = m0 >> 10;
  const int s0 = (m0 & 1023) + wm * 64;
  const int nbb = (n0 + wn * 64) & 255;
  char* shw = (char*)SH + wave * 8192;  // per-wave 8KB restage region
  if (vm) {
    // restage as [n_local 64][s 64] u16 (128B rows, XOR-swizzled)
#pragma unroll
    for (int ni = 0; ni < 4; ++ni) {
      const int nl = ni * 16 + fr;
      const float bias = b2[nbb + nl];
#pragma unroll
      for (int mi = 0; mi < 4; ++mi) {
        u16x4 pk;
#pragma unroll
        for (int r = 0; r < 4; ++r) pk[r] = f2bf(acc[mi][ni][r] + bias);
        *(u16x4*)(shw + nl * 128 + (((mi * 16 + kg * 4) * 2) ^ ((nl & 7) << 4))) = pk;
      }
    }
    const int l8 = lane >> 3, seg8 = lane & 7;
#pragma unroll
    for (int i = 0; i < 8; ++i) {
      const int nl = i * 8 + l8;
      const short8 val = *(const short8*)(shw + nl * 128 + ((seg8 * 16) ^ ((nl & 7) << 4)));
      const int hg = (nbb >> 5) + (nl >> 5), dd = nl & 31;
      *(short8*)(vtb + ((bI * 8 + hg) * 32 + dd) * 1024 + s0 + seg8 * 8) = val;
    }
  } else {
    // q/k (transposed acc): restage as [s_local 64][n 64] u16
    const float* bp = (ws == 0) ? b0 : b1;
    u16* dst = (ws == 0) ? qb : kb;
    const float sc = (ws == 0) ? QS2 : 1.0f;
#pragma unroll
    for (int ni = 0; ni < 4; ++ni) {
      const float4 b4 = *(const float4*)(bp + nbb + ni * 16 + kg * 4);
#pragma unroll
      for (int mi = 0; mi < 4; ++mi) {
        const int sl = mi * 16 + fr;
        u16x4 pk;
#pragma unroll
        for (int r = 0; r < 4; ++r) pk[r] = f2bf((acc[mi][ni][r] + b4[r]) * sc);
        *(u16x4*)(shw + sl * 128 + (((ni * 32 + kg * 8)) ^ ((sl & 7) << 4))) = pk;
      }
    }
    const int l4 = lane >> 2, seg = lane & 3;
#pragma unroll
    for (int hh = 0; hh < 2; ++hh) {
#pragma unroll
      for (int g = 0; g < 4; ++g) {
        const int sl = g * 16 + l4;
        const short8 val = *(const short8*)(shw + sl * 128 + ((hh * 64 + seg * 16) ^ ((sl & 7) << 4)));
        const int hg = (nbb >> 5) + hh;
        *(short8*)(dst + ((bI * 8 + hg) * 1024 + s0 + sl) * 32 + seg * 8) = val;
      }
    }
  }
}

// Output projection: 64x128 tile (4 waves of 32x64), 3-stage pipeline, 512 blocks.
__global__ __launch_bounds__(256, 4) void proj_out_k(
    const u16* __restrict__ A, const u16* __restrict__ Wc,
    const float* __restrict__ bo, float* __restrict__ outp) {
  const int lid = (blockIdx.x & 7) * 64 + (blockIdx.x >> 3);  // 512 = 8*64 bijective
  const int m0 = (lid >> 1) * 64;
  const int n0 = (lid & 1) * 128;
  __shared__ u16 SH[18432];  // 36KB = 3 stages x [A 4KB][B 8KB]
  const int tid = threadIdx.x;
  const int wave = tid >> 6, lane = tid & 63;
  const int fr = lane & 15, kg = lane >> 4;
  const int wm = wave >> 1, wn = wave & 1;
  const int l2 = lane >> 2;
  const int sseg = ((lane & 3) ^ (l2 & 3)) * 8;
  const u16* gA = A + (m0 + wave * 16 + l2) * 256 + sseg;
  const u16* gB = Wc + (768 + n0 + wave * 16 + l2) * 256 + sseg;
  const int dstw = wave * 1024;
  const int rsw = (kg * 16) ^ ((fr & 3) << 4);

  f32x4 acc[2][4];
#pragma unroll
  for (int i = 0; i < 2; ++i)
#pragma unroll
    for (int j = 0; j < 4; ++j) acc[i][j] = (f32x4){0.f, 0.f, 0.f, 0.f};

#define OSTG(t, sb)                                                     \
  do {                                                                  \
    glds16(gA + (t) * 32,         (u16*)((char*)SH + (sb) + dstw));     \
    glds16(gB + (t) * 32,         (u16*)((char*)SH + (sb) + 4096 + dstw)); \
    glds16(gB + 16384 + (t) * 32, (u16*)((char*)SH + (sb) + 8192 + dstw)); \
  } while (0)

  OSTG(0, 0);
  OSTG(1, 12288);
#pragma unroll
  for (int it = 0; it < 8; ++it) {
    if (it < 6) OSTG(it + 2, ((it + 2) % 3) * 12288);
    if (it < 6) wait_vm<6>();
    else if (it == 6) wait_vm<3>();
    else wait_vm<0>();
    __builtin_amdgcn_s_barrier();
    const char* abase = (const char*)SH + (it % 3) * 12288;
    const char* bbase = abase + 4096;
    short8 af[2], bf[4];
#pragma unroll
    for (int i = 0; i < 2; ++i)
      af[i] = *(const short8*)(abase + (wm * 32 + i * 16 + fr) * 64 + rsw);
#pragma unroll
    for (int i = 0; i < 4; ++i)
      bf[i] = *(const short8*)(bbase + (wn * 64 + i * 16 + fr) * 64 + rsw);
#pragma unroll
    for (int mi = 0; mi < 2; ++mi)
#pragma unroll
      for (int ni = 0; ni < 4; ++ni)
        acc[mi][ni] = __builtin_amdgcn_mfma_f32_16x16x32_bf16(bf[ni], af[mi], acc[mi][ni], 0, 0, 0);
    __builtin_amdgcn_s_barrier();
  }
#undef OSTG

#pragma unroll
  for (int ni = 0; ni < 4; ++ni) {
    const int n4 = n0 + wn * 64 + ni * 16 + kg * 4;
    const float4 b4 = *(const float4*)(bo + n4);
#pragma unroll
    for (int mi = 0; mi < 2; ++mi) {
      const int m = m0 + wm * 32 + mi * 16 + fr;
      float4 o;
#pragma unroll
      for (int r = 0; r < 4; ++r) o[r] = acc[mi][ni][r] + b4[r];
      *(float4*)(outp + m * 256 + n4) = o;
    }
  }
}

// Flash attention, swapped QK^T. No online max (scores analytically bounded;
// softmax is shift-invariant, exp2 range absorbs it). l via ones-MFMA (lane-aligned
// with O rows). bf16 bias table. Counted-vmcnt staging, 2 raw barriers/iter.
__global__ __launch_bounds__(256, 5) void rel_attn_k(
    const u16* __restrict__ qb, const u16* __restrict__ kb,
    const u16* __restrict__ vtb, const float* __restrict__ btab,
    u16* __restrict__ ao) {
  const int bid0 = blockIdx.x;
  const int lid = (bid0 & 7) * 256 + (bid0 >> 3);  // XCD chunking: same bh -> same XCD
  const int bh = lid >> 4, qt = lid & 15;
  const int h = bh & 7, b = bh >> 3;
  const int q0 = qt * 64;
  __shared__ u16 bias_lb[3972];  // bf16(btab*LOG2E), 7944B
  __shared__ u16 Kl[2][2048];    // [key 64][dk 32] rows 64B, src-preswizzled
  __shared__ u16 Vl[2][2048];    // [d 32][key 64] rows 128B, src-preswizzled
  __shared__ u16 Pl[4][1024];    // per-wave P tile [q 16][key 64], swizzled
  const int tid = threadIdx.x;
  const int wave = tid >> 6, lane = tid & 63;
  const int fr = lane & 15, kg = lane >> 4;

  for (int i = tid; i < NREL; i += 256) bias_lb[i] = f2bf(btab[h * NREL + i] * LOG2E);

  const int krow = tid >> 2;
  const u16* kgsrc = kb + (bh * 1024 + krow) * 32 + ((tid & 3) ^ (krow & 3)) * 8;
  const int vrow = tid >> 3;
  const u16* vgsrc = vtb + (bh * 32 + vrow) * 1024 + ((tid & 7) ^ (vrow & 7)) * 8;
  u16* kld = &Kl[0][0] + wave * 512;
  u16* vld = &Vl[0][0] + wave * 512;

  const int q = q0 + wave * 16 + fr;
  const short8 qf = *(const short8*)(qb + (bh * 1024 + q) * 32 + kg * 8);
  const int qbase = (q >> 5) * 63 + (q & 31) + 1984;
  char* pw = (char*)Pl[wave] + fr * 128;
  const int swz = (fr & 7) << 4;

  short8 ones;
#pragma unroll
  for (int j = 0; j < 8; ++j) ones[j] = (short)0x3F80;  // bf16 1.0

  f32x4 oacc[2], lacc;
  oacc[0] = (f32x4){0.f, 0.f, 0.f, 0.f};
  oacc[1] = (f32x4){0.f, 0.f, 0.f, 0.f};
  lacc = (f32x4){0.f, 0.f, 0.f, 0.f};

  glds16(kgsrc, kld);
  glds16(vgsrc, vld);
  __syncthreads();  // bias_lb ready + stage0 drained (only full drain in kernel)

  for (int kt = 0; kt < 16; ++kt) {
    const int cur = kt & 1;
    if (kt < 15) {
      glds16(kgsrc + (kt + 1) * 2048, kld + (cur ^ 1) * 2048);
      glds16(vgsrc + (kt + 1) * 64, vld + (cur ^ 1) * 2048);
      wait_vm<2>();  // stage kt landed; stage kt+1 stays in flight
    } else {
      wait_vm<0>();
    }
    __builtin_amdgcn_s_barrier();

    const char* kbase = (const char*)Kl[cur];
    const char* vbase = (const char*)Vl[cur];
    short8 kf[4], vf[2][2];
#pragma unroll
    for (int g = 0; g < 4; ++g)
      kf[g] = *(const short8*)(kbase + (g * 16 + fr) * 64 + ((kg * 16) ^ ((fr & 3) << 4)));
#pragma unroll
    for (int ks = 0; ks < 2; ++ks)
#pragma unroll
      for (int g2 = 0; g2 < 2; ++g2)
        vf[ks][g2] = *(const short8*)(vbase + (g2 * 16 + fr) * 128 + (((ks * 4 + kg) << 4) ^ swz));

    // S^T = K.Q (row=key, col=q=fr); scale*log2e folded into q
    f32x4 sacc[4];
    __builtin_amdgcn_s_setprio(1);
#pragma unroll
    for (int g = 0; g < 4; ++g)
      sacc[g] = __builtin_amdgcn_mfma_f32_16x16x32_bf16(kf[g], qf, (f32x4){0.f, 0.f, 0.f, 0.f}, 0, 0, 0);
    __builtin_amdgcn_s_setprio(0);

    // p = exp2(s + bias); bias idx = qbase - key - 31*ki (4 consecutive per g)
    const int t0 = qbase - kt * 126 - kg * 4;
    u32 pk[4][2];
#pragma unroll
    for (int g = 0; g < 4; ++g) {
      const int ag = t0 - g * 16 - 31 * (g >> 1);
      float e[4];
#pragma unroll
      for (int r = 0; r < 4; ++r) {
        union { u32 u; float f; } bc;
        bc.u = (u32)bias_lb[ag - r] << 16;
        e[r] = fast_exp2(sacc[g][r] + bc.f);
      }
      pk[g][0] = cvt_pk_bf16(e[0], e[1]);
      pk[g][1] = cvt_pk_bf16(e[2], e[3]);
    }

    // stage P (same-wave DS ops are ordered; no barrier needed)
#pragma unroll
    for (int g = 0; g < 4; ++g) {
      u32x2 w2;
      w2[0] = pk[g][0];
      w2[1] = pk[g][1];
      *(u32x2*)(pw + ((g * 32 + kg * 8) ^ swz)) = w2;
    }

    // O += P.V ; l += P.1 (row sums land lane-aligned with O rows)
#pragma unroll
    for (int ks = 0; ks < 2; ++ks) {
      const short8 pf = *(const short8*)(pw + ((ks * 64 + kg * 16) ^ swz));
      __builtin_amdgcn_s_setprio(1);
      oacc[0] = __builtin_amdgcn_mfma_f32_16x16x32_bf16(pf, vf[ks][0], oacc[0], 0, 0, 0);
      oacc[1] = __builtin_amdgcn_mfma_f32_16x16x32_bf16(pf, vf[ks][1], oacc[1], 0, 0, 0);
      lacc = __builtin_amdgcn_mfma_f32_16x16x32_bf16(pf, ones, lacc, 0, 0, 0);
      __builtin_amdgcn_s_setprio(0);
    }
    __builtin_amdgcn_s_barrier();  // all reads of buf[cur] done before next prefetch
  }

  // epilogue: divide by l (lane-aligned), restage O through Pl, coalesced stores
#pragma unroll
  for (int r = 0; r < 4; ++r) {
    const float inv = __builtin_amdgcn_rcpf(lacc[r]);
#pragma unroll
    for (int g2 = 0; g2 < 2; ++g2)
      *(u16*)((char*)Pl[wave] + (kg * 4 + r) * 64 + (g2 * 16 + fr) * 2) =
          f2bf(oacc[g2][r] * inv);
  }
  const int orow = lane >> 2, oseg = lane & 3;
  const short8 ov = *(const short8*)((char*)Pl[wave] + orow * 64 + oseg * 16);
  *(short8*)(ao + (b * 1024 + q0 + wave * 16 + orow) * 256 + h * 32 + oseg * 8) = ov;
}

extern "C" void kernel_launch(void* const* d_in, const int* in_sizes, int n_in,
                              void* d_out, int out_size, void* d_ws, size_t ws_size,
                              hipStream_t stream) {
  (void)in_sizes; (void)n_in; (void)out_size; (void)ws_size;
  const float* x    = (const float*)d_in[0];
  const float* Wq   = (const float*)d_in[1];
  const float* bq   = (const float*)d_in[2];
  const float* Wk   = (const float*)d_in[3];
  const float* bk   = (const float*)d_in[4];
  const float* Wv   = (const float*)d_in[5];
  const float* bv   = (const float*)d_in[6];
  const float* Wo   = (const float*)d_in[7];
  const float* bo   = (const float*)d_in[8];
  const float* btab = (const float*)d_in[9];
  // d_in[10] (rel_index) unused: recomputed analytically in-kernel.
  float* out = (float*)d_out;
  char* ws = (char*)d_ws;

  u16* xbf  = (u16*)(ws + 0);          // also attn_out after rel_attn_k
  u16* Wcat = (u16*)(ws + 8388608);
  u16* qbuf = (u16*)(ws + 8912896);
  u16* kbuf = (u16*)(ws + 17301504);
  u16* vtb  = (u16*)(ws + 25690112);

  cast_all_k<<<4352, 256, 0, stream>>>((const float4*)x, Wq, Wk, Wv, Wo,
                                       (u16x4*)xbf, (u16x4*)Wcat);
  proj_qkv_k<<<768, 256, 0, stream>>>(xbf, Wcat, bq, bk, bv, qbuf, kbuf, vtb);
  rel_attn_k<<<2048, 256, 0, stream>>>(qbuf, kbuf, vtb, btab, xbf);
  proj_out_k<<<512, 256, 0, stream>>>(xbf, Wcat, bo, out);
}